// Round 7
// baseline (623.712 us; speedup 1.0000x reference)
//
#include <hip/hip_runtime.h>
#include <cmath>

#define NPTS   1048576
#define NLVL   16
#define NLOW   5                 // levels 0..4: small-footprint tables
#define T      (1u << 19)
#define TMASK  (T - 1u)
#define P1     2654435761u
#define P2     805459861u

typedef float v2f __attribute__((ext_vector_type(2)));
typedef float v4f __attribute__((ext_vector_type(4)));

struct Corners { uint32_t h[8]; float wt[8]; };

// Must match fp32 reference arithmetic exactly (same ops/order as the
// passing R1-R6 kernels).
__device__ __forceinline__ Corners mk_corners(float px, float py, float pz, float rf) {
    Corners cc;
    const float xs0 = px * rf, xs1 = py * rf, xs2 = pz * rf;
    const float f0 = floorf(xs0), f1 = floorf(xs1), f2 = floorf(xs2);
    const float w0 = xs0 - f0, w1 = xs1 - f1, w2 = xs2 - f2;
    const uint32_t i0 = (uint32_t)f0, i1 = (uint32_t)f1, i2 = (uint32_t)f2;
    const uint32_t A0 = i0,      A1 = i0 + 1u;
    const uint32_t B0 = i1 * P1, B1 = B0 + P1;
    const uint32_t C0 = i2 * P2, C1 = C0 + P2;
    cc.h[0] = (A0 ^ B0 ^ C0) & TMASK;  cc.h[1] = (A0 ^ B0 ^ C1) & TMASK;
    cc.h[2] = (A0 ^ B1 ^ C0) & TMASK;  cc.h[3] = (A0 ^ B1 ^ C1) & TMASK;
    cc.h[4] = (A1 ^ B0 ^ C0) & TMASK;  cc.h[5] = (A1 ^ B0 ^ C1) & TMASK;
    cc.h[6] = (A1 ^ B1 ^ C0) & TMASK;  cc.h[7] = (A1 ^ B1 ^ C1) & TMASK;
    const float u0 = 1.0f - w0, u1 = 1.0f - w1, u2 = 1.0f - w2;
    cc.wt[0] = (u0 * u1) * u2;  cc.wt[1] = (u0 * u1) * w2;
    cc.wt[2] = (u0 * w1) * u2;  cc.wt[3] = (u0 * w1) * w2;
    cc.wt[4] = (w0 * u1) * u2;  cc.wt[5] = (w0 * u1) * w2;
    cc.wt[6] = (w0 * w1) * u2;  cc.wt[7] = (w0 * w1) * w2;
    return cc;
}

// Low level: 1 point/thread, full-range gather (table L1/L2-trivial),
// dense NT store into the level's ws slice.
__global__ __launch_bounds__(256) void hashgrid_lvl1(
    const float* __restrict__ x,
    const float* __restrict__ tb,
    float* __restrict__ wsl,
    float rf)
{
    const int n = blockIdx.x * 256 + threadIdx.x;
    const float px = __builtin_nontemporal_load(x + 3 * (size_t)n + 0);
    const float py = __builtin_nontemporal_load(x + 3 * (size_t)n + 1);
    const float pz = __builtin_nontemporal_load(x + 3 * (size_t)n + 2);
    const Corners cc = mk_corners(px, py, pz, rf);
    float a0 = 0.f, a1 = 0.f;
#pragma unroll
    for (int c = 0; c < 8; ++c) {
        const float2 g = *(const float2*)(tb + 2 * (size_t)cc.h[c]);
        a0 += cc.wt[c] * g.x;
        a1 += cc.wt[c] * g.y;
    }
    v2f r; r.x = a0; r.y = a1;
    __builtin_nontemporal_store(r, (v2f*)(wsl + (size_t)n * 2));
}

// Heavy level: 4 points/thread -> 32 independent gathers in flight,
// quarter the waves, amortized overhead. Dense NT ws stores.
__global__ __launch_bounds__(256) void hashgrid_lvl4pt(
    const float* __restrict__ x,
    const float* __restrict__ tb,
    float* __restrict__ wsl,
    float rf)
{
    const int t = blockIdx.x * 256 + threadIdx.x;   // NPTS/4 threads

    float a0[4], a1[4];
#pragma unroll
    for (int p = 0; p < 4; ++p) {
        const int n = t + p * (NPTS / 4);
        const float px = __builtin_nontemporal_load(x + 3 * (size_t)n + 0);
        const float py = __builtin_nontemporal_load(x + 3 * (size_t)n + 1);
        const float pz = __builtin_nontemporal_load(x + 3 * (size_t)n + 2);
        const Corners cc = mk_corners(px, py, pz, rf);
        float s0 = 0.f, s1 = 0.f;
#pragma unroll
        for (int c = 0; c < 8; ++c) {
            const float2 g = *(const float2*)(tb + 2 * (size_t)cc.h[c]);
            s0 += cc.wt[c] * g.x;
            s1 += cc.wt[c] * g.y;
        }
        a0[p] = s0; a1[p] = s1;
    }
#pragma unroll
    for (int p = 0; p < 4; ++p) {
        const int n = t + p * (NPTS / 4);
        v2f r; r.x = a0[p]; r.y = a1[p];
        __builtin_nontemporal_store(r, (v2f*)(wsl + (size_t)n * 2));
    }
}

// ws [16][N][2] -> out [N][32]. NT loads (read-once), cached stores so L2
// merges each thread's 8x16B into one full 128B line.
__global__ __launch_bounds__(256) void hashgrid_transpose(
    const float* __restrict__ ws,
    float* __restrict__ out)
{
    const int n = blockIdx.x * 256 + threadIdx.x;
    float acc[2 * NLVL];
#pragma unroll
    for (int l = 0; l < NLVL; ++l) {
        const v2f g = __builtin_nontemporal_load(
            (const v2f*)(ws + ((size_t)l << 21) + (size_t)n * 2));
        acc[2 * l + 0] = g.x;
        acc[2 * l + 1] = g.y;
    }
    v4f* op = (v4f*)(out + (size_t)n * 32);
#pragma unroll
    for (int k = 0; k < 8; ++k) {
        v4f v; v.x = acc[4*k]; v.y = acc[4*k+1]; v.z = acc[4*k+2]; v.w = acc[4*k+3];
        op[k] = v;
    }
}

// Fallback (no usable ws): one kernel per level, direct strided-out writes.
__global__ __launch_bounds__(256) void hashgrid_lvl_direct(
    const float* __restrict__ x,
    const float* __restrict__ tb,
    float* __restrict__ outl,
    float rf)
{
    const int n = blockIdx.x * 256 + threadIdx.x;
    const float px = __builtin_nontemporal_load(x + 3 * (size_t)n + 0);
    const float py = __builtin_nontemporal_load(x + 3 * (size_t)n + 1);
    const float pz = __builtin_nontemporal_load(x + 3 * (size_t)n + 2);
    const Corners cc = mk_corners(px, py, pz, rf);
    float a0 = 0.f, a1 = 0.f;
#pragma unroll
    for (int c = 0; c < 8; ++c) {
        const float2 g = *(const float2*)(tb + 2 * (size_t)cc.h[c]);
        a0 += cc.wt[c] * g.x;
        a1 += cc.wt[c] * g.y;
    }
    outl[(size_t)n * 32 + 0] = a0;
    outl[(size_t)n * 32 + 1] = a1;
}

extern "C" void kernel_launch(void* const* d_in, const int* in_sizes, int n_in,
                              void* d_out, int out_size, void* d_ws, size_t ws_size,
                              hipStream_t stream) {
    const float* x     = (const float*)d_in[0];
    const float* table = (const float*)d_in[1];
    float* out         = (float*)d_out;
    float* ws          = (float*)d_ws;

    // Reproduce Python's RESOLUTIONS bit-exactly using the same libm
    // (volatile fn pointers stop clang from folding/strength-reducing pow).
    double (*volatile p_log)(double)          = log;
    double (*volatile p_exp)(double)          = exp;
    double (*volatile p_pow)(double, double)  = pow;
    double (*volatile p_floor)(double)        = floor;

    const double b = p_exp((p_log(2048.0) - p_log(16.0)) / 15.0);
    float rf[NLVL];
    for (int l = 0; l < NLVL; ++l)
        rf[l] = (float)(int)p_floor(16.0 * p_pow(b, (double)l));

    const bool use_ws = ws_size >= (size_t)NLVL * NPTS * 2 * sizeof(float);

    if (!use_ws) {
        for (int l = 0; l < NLVL; ++l)
            hashgrid_lvl_direct<<<NPTS / 256, 256, 0, stream>>>(
                x, table + ((size_t)l << 20), out + 2 * l, rf[l]);
        return;
    }

    // heavy levels first (long pole), then cheap low levels, then transpose
    for (int l = NLOW; l < NLVL; ++l) {
        hashgrid_lvl4pt<<<NPTS / 1024, 256, 0, stream>>>(
            x, table + ((size_t)l << 20), ws + ((size_t)l << 21), rf[l]);
    }
    for (int l = 0; l < NLOW; ++l) {
        hashgrid_lvl1<<<NPTS / 256, 256, 0, stream>>>(
            x, table + ((size_t)l << 20), ws + ((size_t)l << 21), rf[l]);
    }
    hashgrid_transpose<<<NPTS / 256, 256, 0, stream>>>(ws, out);
}

// Round 8
// 560.343 us; speedup vs baseline: 1.1131x; 1.1131x over previous
//
#include <hip/hip_runtime.h>
#include <cmath>

#define NPTS   1048576
#define NLVL   16
#define NLOW   5                 // levels 0..4: small-footprint tables
#define T      (1u << 19)
#define TMASK  (T - 1u)
#define P1     2654435761u
#define P2     805459861u

typedef float    v2f __attribute__((ext_vector_type(2)));
typedef float    v4f __attribute__((ext_vector_type(4)));
typedef _Float16 v2h __attribute__((ext_vector_type(2)));
typedef _Float16 v4h __attribute__((ext_vector_type(4)));

struct Corners { uint32_t h[8]; float wt[8]; };

// Must match fp32 reference arithmetic exactly (same ops/order as the
// passing R1-R7 kernels).
__device__ __forceinline__ Corners mk_corners(float px, float py, float pz, float rf) {
    Corners cc;
    const float xs0 = px * rf, xs1 = py * rf, xs2 = pz * rf;
    const float f0 = floorf(xs0), f1 = floorf(xs1), f2 = floorf(xs2);
    const float w0 = xs0 - f0, w1 = xs1 - f1, w2 = xs2 - f2;
    const uint32_t i0 = (uint32_t)f0, i1 = (uint32_t)f1, i2 = (uint32_t)f2;
    const uint32_t A0 = i0,      A1 = i0 + 1u;
    const uint32_t B0 = i1 * P1, B1 = B0 + P1;
    const uint32_t C0 = i2 * P2, C1 = C0 + P2;
    cc.h[0] = (A0 ^ B0 ^ C0) & TMASK;  cc.h[1] = (A0 ^ B0 ^ C1) & TMASK;
    cc.h[2] = (A0 ^ B1 ^ C0) & TMASK;  cc.h[3] = (A0 ^ B1 ^ C1) & TMASK;
    cc.h[4] = (A1 ^ B0 ^ C0) & TMASK;  cc.h[5] = (A1 ^ B0 ^ C1) & TMASK;
    cc.h[6] = (A1 ^ B1 ^ C0) & TMASK;  cc.h[7] = (A1 ^ B1 ^ C1) & TMASK;
    const float u0 = 1.0f - w0, u1 = 1.0f - w1, u2 = 1.0f - w2;
    cc.wt[0] = (u0 * u1) * u2;  cc.wt[1] = (u0 * u1) * w2;
    cc.wt[2] = (u0 * w1) * u2;  cc.wt[3] = (u0 * w1) * w2;
    cc.wt[4] = (w0 * u1) * u2;  cc.wt[5] = (w0 * u1) * w2;
    cc.wt[6] = (w0 * w1) * u2;  cc.wt[7] = (w0 * w1) * w2;
    return cc;
}

// Heavy level: 2 ADJACENT points/thread (16 gathers in flight), grid 2048
// blocks -> full occupancy (R6-measured best MLP point). fp16 ws staging:
// one 8B NT store for both points.
__global__ __launch_bounds__(256) void hashgrid_lvl2pt(
    const float* __restrict__ x,
    const float* __restrict__ tb,      // table + lvl*T*F
    _Float16* __restrict__ wsl,        // ws slice [N][2] fp16
    float rf)
{
    const int t = blockIdx.x * 256 + threadIdx.x;   // 0 .. NPTS/2

    // contiguous 24B of x for points 2t, 2t+1 (8B-aligned)
    const v2f q0 = __builtin_nontemporal_load((const v2f*)(x + 6 * (size_t)t + 0));
    const v2f q1 = __builtin_nontemporal_load((const v2f*)(x + 6 * (size_t)t + 2));
    const v2f q2 = __builtin_nontemporal_load((const v2f*)(x + 6 * (size_t)t + 4));

    const Corners c0 = mk_corners(q0.x, q0.y, q1.x, rf);
    const Corners c1 = mk_corners(q1.y, q2.x, q2.y, rf);

    float a00 = 0.f, a01 = 0.f, a10 = 0.f, a11 = 0.f;
#pragma unroll
    for (int c = 0; c < 8; ++c) {
        const float2 g0 = *(const float2*)(tb + 2 * (size_t)c0.h[c]);
        const float2 g1 = *(const float2*)(tb + 2 * (size_t)c1.h[c]);
        a00 += c0.wt[c] * g0.x;  a01 += c0.wt[c] * g0.y;
        a10 += c1.wt[c] * g1.x;  a11 += c1.wt[c] * g1.y;
    }
    v4h r;
    r.x = (_Float16)a00;  r.y = (_Float16)a01;   // point 2t
    r.z = (_Float16)a10;  r.w = (_Float16)a11;   // point 2t+1
    __builtin_nontemporal_store(r, (v4h*)(wsl + 4 * (size_t)t));
}

// Low level: 1 point/thread, table is cache-trivial. fp16 NT ws store.
__global__ __launch_bounds__(256) void hashgrid_lvl1(
    const float* __restrict__ x,
    const float* __restrict__ tb,
    _Float16* __restrict__ wsl,
    float rf)
{
    const int n = blockIdx.x * 256 + threadIdx.x;
    const float px = __builtin_nontemporal_load(x + 3 * (size_t)n + 0);
    const float py = __builtin_nontemporal_load(x + 3 * (size_t)n + 1);
    const float pz = __builtin_nontemporal_load(x + 3 * (size_t)n + 2);
    const Corners cc = mk_corners(px, py, pz, rf);
    float a0 = 0.f, a1 = 0.f;
#pragma unroll
    for (int c = 0; c < 8; ++c) {
        const float2 g = *(const float2*)(tb + 2 * (size_t)cc.h[c]);
        a0 += cc.wt[c] * g.x;
        a1 += cc.wt[c] * g.y;
    }
    v2h r; r.x = (_Float16)a0; r.y = (_Float16)a1;
    __builtin_nontemporal_store(r, (v2h*)(wsl + 2 * (size_t)n));
}

// ws fp16 [16][N][2] -> out fp32 [N][32]. NT loads (read-once), cached
// stores so L2 merges each thread's 8x16B into one full 128B line.
__global__ __launch_bounds__(256) void hashgrid_transpose(
    const _Float16* __restrict__ ws,
    float* __restrict__ out)
{
    const int n = blockIdx.x * 256 + threadIdx.x;
    float acc[2 * NLVL];
#pragma unroll
    for (int l = 0; l < NLVL; ++l) {
        const v2h g = __builtin_nontemporal_load(
            (const v2h*)(ws + ((size_t)l << 21) + (size_t)n * 2));
        acc[2 * l + 0] = (float)g.x;
        acc[2 * l + 1] = (float)g.y;
    }
    v4f* op = (v4f*)(out + (size_t)n * 32);
#pragma unroll
    for (int k = 0; k < 8; ++k) {
        v4f v; v.x = acc[4*k]; v.y = acc[4*k+1]; v.z = acc[4*k+2]; v.w = acc[4*k+3];
        op[k] = v;
    }
}

// Fallback (no usable ws): one kernel per level, direct strided-out writes.
__global__ __launch_bounds__(256) void hashgrid_lvl_direct(
    const float* __restrict__ x,
    const float* __restrict__ tb,
    float* __restrict__ outl,
    float rf)
{
    const int n = blockIdx.x * 256 + threadIdx.x;
    const float px = __builtin_nontemporal_load(x + 3 * (size_t)n + 0);
    const float py = __builtin_nontemporal_load(x + 3 * (size_t)n + 1);
    const float pz = __builtin_nontemporal_load(x + 3 * (size_t)n + 2);
    const Corners cc = mk_corners(px, py, pz, rf);
    float a0 = 0.f, a1 = 0.f;
#pragma unroll
    for (int c = 0; c < 8; ++c) {
        const float2 g = *(const float2*)(tb + 2 * (size_t)cc.h[c]);
        a0 += cc.wt[c] * g.x;
        a1 += cc.wt[c] * g.y;
    }
    outl[(size_t)n * 32 + 0] = a0;
    outl[(size_t)n * 32 + 1] = a1;
}

extern "C" void kernel_launch(void* const* d_in, const int* in_sizes, int n_in,
                              void* d_out, int out_size, void* d_ws, size_t ws_size,
                              hipStream_t stream) {
    const float* x     = (const float*)d_in[0];
    const float* table = (const float*)d_in[1];
    float* out         = (float*)d_out;
    _Float16* ws       = (_Float16*)d_ws;

    // Reproduce Python's RESOLUTIONS bit-exactly using the same libm
    // (volatile fn pointers stop clang from folding/strength-reducing pow).
    double (*volatile p_log)(double)          = log;
    double (*volatile p_exp)(double)          = exp;
    double (*volatile p_pow)(double, double)  = pow;
    double (*volatile p_floor)(double)        = floor;

    const double b = p_exp((p_log(2048.0) - p_log(16.0)) / 15.0);
    float rf[NLVL];
    for (int l = 0; l < NLVL; ++l)
        rf[l] = (float)(int)p_floor(16.0 * p_pow(b, (double)l));

    const bool use_ws = ws_size >= (size_t)NLVL * NPTS * 2 * sizeof(_Float16);

    if (!use_ws) {
        for (int l = 0; l < NLVL; ++l)
            hashgrid_lvl_direct<<<NPTS / 256, 256, 0, stream>>>(
                x, table + ((size_t)l << 20), out + 2 * l, rf[l]);
        return;
    }

    // heavy levels first (long pole), then cheap low levels, then transpose
    for (int l = NLOW; l < NLVL; ++l) {
        hashgrid_lvl2pt<<<NPTS / 512, 256, 0, stream>>>(
            x, table + ((size_t)l << 20), ws + ((size_t)l << 21), rf[l]);
    }
    for (int l = 0; l < NLOW; ++l) {
        hashgrid_lvl1<<<NPTS / 256, 256, 0, stream>>>(
            x, table + ((size_t)l << 20), ws + ((size_t)l << 21), rf[l]);
    }
    hashgrid_transpose<<<NPTS / 256, 256, 0, stream>>>(ws, out);
}